// Round 8
// baseline (195.998 us; speedup 1.0000x reference)
//
#include <hip/hip_runtime.h>
#include <stdint.h>

// ---------------------------------------------------------------------------
// SNN EMNIST forward: T=10, B=4096, IN=784, HID=256, NCLS=47
// R19: saturate the VALU issue port during the hash phase.
// R16-R18 all show VALUBusy ~59-61% / VGPR ~96: each thread exposes only 2
// threefry chains (one hash2) and there are 2 waves/SIMD -> 4 chains per
// issue port = starvation at ~4-6cyc dep latency. (Standalone spikegen: 8
// chains x ~5 waves/SIMD -> 82% busy.) The compiler packs registers tight
// (VGPR 96) and serializes the 5 hash2 tasks.
// Change: per-slab hash rewritten as round-lockstep over h0[10],h1[10] (all
// 10 chains advance together; full unroll, static indices). Init, rounds,
// injections, final xor, compare, output words and destinations byte-
// identical -> I bitwise identical -> absmax stays 4.882812e-4. Frag preload
// moved after the hash (keeps hash-phase pressure under the cap). Tail guard
// on the x-load only (xx=0 => compare false => bits 0, same result).
// K-loop structure, staging, epilogue, splitk otherwise unchanged from R18.
// ---------------------------------------------------------------------------

#define T_STEPS 10
#define BATCH   4096
#define IN_DIM  784
#define HID     256
#define NCLS    47
#define NROWS   (T_STEPS * BATCH)        // 40960
#define KWORDS  25                       // ceil(784/32)
#define KPAD    800                      // 25*32
#define M_TILE  160

// d_ws layout (bytes):
//   [46039040, ...)        W1{hi,mid,lo}T : bf16 [256][800], 409600 B each
#define WS_W1HI_OFF 46039040u
#define WS_W1MD_OFF (46039040u + 409600u)
#define WS_W1LO_OFF (46039040u + 819200u)

typedef __attribute__((ext_vector_type(8))) short    bf16x8;
typedef __attribute__((ext_vector_type(4))) float    f32x4;
typedef __attribute__((ext_vector_type(4))) uint32_t u32x4;

__device__ __forceinline__ uint32_t rotl32(uint32_t x, uint32_t r) {
    return __builtin_amdgcn_alignbit(x, x, 32u - r);
}

// JAX threefry2x32, key=(0,42), partitionable scheme: out = o0^o1, x0=0, x1=i.
// (Scalar reference form; the K-loop uses the 10-chain interleaved expansion
// below, which is instruction-for-instruction the same recurrence.)
__device__ __forceinline__ uint32_t tf_hash(uint32_t lo) {
    const uint32_t ks1 = 42u;
    const uint32_t ks2 = 0x1BD11BDAu ^ 42u;
    uint32_t x0 = 0u;
    uint32_t x1 = lo + ks1;
#define TF_RND(r) { x0 += x1; x1 = rotl32(x1, r); x1 ^= x0; }
    TF_RND(13) TF_RND(15) TF_RND(26) TF_RND(6)
    x0 += ks1; x1 += ks2 + 1u;
    TF_RND(17) TF_RND(29) TF_RND(16) TF_RND(24)
    x0 += ks2; x1 += 2u;                       // ks0 == 0
    TF_RND(13) TF_RND(15) TF_RND(26) TF_RND(6)
    x1 += ks1 + 3u;                            // x0 += ks0 is a no-op
    TF_RND(17) TF_RND(29) TF_RND(16) TF_RND(24)
    x0 += ks1; x1 += ks2 + 4u;
    TF_RND(13) TF_RND(15) TF_RND(26) TF_RND(6)
    x0 += ks2; x1 += 5u;                       // ks0 == 0
#undef TF_RND
    return x0 ^ x1;
}

// ---------------------------------------------------------------------------
// Kernel B0: split W1 (f32 [784][256]) into transposed bf16 hi/mid/lo
// [256][800]. EXACT: hi+mid+lo == w bitwise.
// ---------------------------------------------------------------------------
__global__ __launch_bounds__(256) void splitk_k(
        const float* __restrict__ W1, ushort* __restrict__ hiT,
        ushort* __restrict__ midT, ushort* __restrict__ loT) {
    int n = blockIdx.x;                  // 0..255
    for (int k = threadIdx.x; k < KPAD; k += 256) {
        float w = (k < IN_DIM) ? W1[k * HID + n] : 0.0f;
        uint32_t u = __float_as_uint(w);
        uint32_t hb = (u + 0x7FFFu + ((u >> 16) & 1u)) >> 16;    // RNE to bf16
        float hf = __uint_as_float(hb << 16);
        float r1 = w - hf;                                       // exact
        uint32_t u1 = __float_as_uint(r1);
        uint32_t mb = (u1 + 0x7FFFu + ((u1 >> 16) & 1u)) >> 16;  // RNE
        float mf2 = __uint_as_float(mb << 16);
        float r2 = r1 - mf2;                                     // exact
        uint32_t u2 = __float_as_uint(r2);
        uint32_t lb = (u2 + 0x7FFFu + ((u2 >> 16) & 1u)) >> 16;  // exact fit
        hiT [n * KPAD + k] = (ushort)hb;
        midT[n * KPAD + k] = (ushort)mb;
        loT [n * KPAD + k] = (ushort)lb;
    }
}

// ---------------------------------------------------------------------------
// Fused spikegen + GEMM + LIF scan + readout.
// Block: 16 batch rows x 10 timesteps = 160 tile rows x 256 cols, 512
// threads = 8 waves (2M x 4N), wave = 80x64 = 5x4 tiles of 16x16x32.
// Tile row r = t*16 + j: t = r>>4, b = b0 + (r&15). Grid 256 = 1 block/CU.
// Per slab: STAGE_B(next) -> HASH10 (10 interleaved chains -> 5 ds_write)
// -> PRELOAD 17 frags (cur) -> 60 MFMA -> barrier, flip.
// Epilogue identical to R18 (in-LDS LIF scan + readout, no I_all).
// ---------------------------------------------------------------------------
#define LDS_B0  20480
#define B_BUFSZ 49152
#define A_BUFSZ 10240
#define I0_LDW  258                      // i0 row pitch (floats)
#define G_LDW   260                      // g row pitch (floats)
#define G_OFF   83200                    // after i0: 80*258*4 = 82560, pad up

#define KS1 42u
#define KS2 (0x1BD11BDAu ^ 42u)

__global__ __launch_bounds__(512, 1) void fused_gemm_k(
        const ushort* __restrict__ hiT, const ushort* __restrict__ midT,
        const ushort* __restrict__ loT, const float* __restrict__ b1,
        const float* __restrict__ x, const float* __restrict__ Wr,
        const float* __restrict__ br, float* __restrict__ out) {
    __shared__ __align__(16) char lds[118784];   // 116 KB, 1 block/CU

    const int tid = threadIdx.x;
    const int l   = tid & 63;
    const int wv  = tid >> 6;        // 0..7
    const int wm  = wv >> 2;         // 0..1 (M half: t 0-4 vs 5-9)
    const int wn  = wv & 3;          // 0..3 (N quarter)
    const int b0  = blockIdx.x << 4; // 16 batch rows per block

    f32x4 acc[5][4] = {};

    // fragment read addressing (shared swizzle sig for A and B)
    const int q   = l >> 4;
    const int sig = q ^ (l & 3) ^ ((l >> 2) & 3);
    const int a_rd = wm * 5120 + ((l & 15) << 6) + (sig << 4);      // in A buf
    const int b_rd = (((wn << 6) + (l & 15)) << 6) + (sig << 4);    // in plane

    // ---- B staging: 1024 slots of 16B per plane, 2 per thread ----
    const ushort* hi_p[2];
    const ushort* md_p[2];
    const ushort* lo_p[2];
    int bdst[2];
#pragma unroll
    for (int i = 0; i < 2; ++i) {
        int s  = (i << 9) + tid;
        int n  = s >> 2;
        int qs = s & 3;
        int qd = qs ^ (n & 3) ^ ((n >> 2) & 3);
        size_t eoff = (size_t)n * KPAD + ((size_t)qd << 3);
        hi_p[i] = hiT  + eoff;
        md_p[i] = midT + eoff;
        lo_p[i] = loT  + eoff;
        bdst[i] = ((i << 9) + (wv << 6)) << 4;    // wave-uniform base
    }

    // ---- A expansion: 2560 hash2 tasks/slab = exactly 5 per thread. ----
    // Task tau = tid + 512*s: tile row = tau>>4 (0..159), pair p = tau&15.
    // Global row g = (row>>4)*4096 + b0 + (row&15)  [r = t*16 + j mapping].
    int      adst[5];
    const float* txp[5];
    uint32_t tib[5];
    int      tpp[5];
#pragma unroll
    for (int s = 0; s < 5; ++s) {
        int tau = tid + (s << 9);
        int row = tau >> 4;
        int p   = tau & 15;
        int qd  = (p >> 2) ^ (row & 3) ^ ((row >> 2) & 3);
        adst[s] = (row << 6) + (qd << 4) + ((p & 3) << 2);
        int rowg = ((row >> 4) * BATCH) + b0 + (row & 15);
        txp[s]  = x + (size_t)(b0 + (row & 15)) * IN_DIM + (p << 1);
        tib[s]  = (uint32_t)rowg * (uint32_t)IN_DIM + (uint32_t)(p << 1);
        tpp[s]  = p;
    }

#define STAGE_B(koff, bbase) \
    _Pragma("unroll") \
    for (int i = 0; i < 2; ++i) { \
        __builtin_amdgcn_global_load_lds( \
            (const __attribute__((address_space(1))) void*)(hi_p[i] + (koff)), \
            (__attribute__((address_space(3))) void*)(lds + (bbase) + bdst[i]), \
            16, 0, 0); \
        __builtin_amdgcn_global_load_lds( \
            (const __attribute__((address_space(1))) void*)(md_p[i] + (koff)), \
            (__attribute__((address_space(3))) void*)(lds + (bbase) + 16384 + bdst[i]), \
            16, 0, 0); \
        __builtin_amdgcn_global_load_lds( \
            (const __attribute__((address_space(1))) void*)(lo_p[i] + (koff)), \
            (__attribute__((address_space(3))) void*)(lds + (bbase) + 32768 + bdst[i]), \
            16, 0, 0); \
    }

// ---- 10-chain round-lockstep threefry + compare + 5 ds_write_b32 ----
// Chain c: task s = c>>1, element e = c&1, input lo = tib[s]+koff+e.
// Recurrence identical to tf_hash; output word identical to hash2's.
#define TFR_ALL(r) \
    _Pragma("unroll") \
    for (int c = 0; c < 10; ++c) { \
        h0[c] += h1[c]; h1[c] = rotl32(h1[c], r); h1[c] ^= h0[c]; }
#define INJ_ALL(a, b) \
    _Pragma("unroll") \
    for (int c = 0; c < 10; ++c) { h0[c] += (a); h1[c] += (b); }

#define HASH10(koff, abase, is_tail) { \
    float    xa[5], xb[5]; \
    uint32_t h0[10], h1[10]; \
    _Pragma("unroll") \
    for (int s = 0; s < 5; ++s) { \
        bool safe = !(is_tail) || (tpp[s] < 8); \
        if (safe) { float2 t_ = *(const float2*)(txp[s] + (koff)); \
                    xa[s] = t_.x; xb[s] = t_.y; } \
        else      { xa[s] = 0.f;  xb[s] = 0.f; } \
        uint32_t lo0 = tib[s] + (uint32_t)(koff); \
        h0[2*s]   = 0u; h1[2*s]   = lo0 + KS1; \
        h0[2*s+1] = 0u; h1[2*s+1] = lo0 + 1u + KS1; \
    } \
    TFR_ALL(13) TFR_ALL(15) TFR_ALL(26) TFR_ALL(6) \
    INJ_ALL(KS1, KS2 + 1u) \
    TFR_ALL(17) TFR_ALL(29) TFR_ALL(16) TFR_ALL(24) \
    INJ_ALL(KS2, 2u) \
    TFR_ALL(13) TFR_ALL(15) TFR_ALL(26) TFR_ALL(6) \
    INJ_ALL(0u, KS1 + 3u) \
    TFR_ALL(17) TFR_ALL(29) TFR_ALL(16) TFR_ALL(24) \
    INJ_ALL(KS1, KS2 + 4u) \
    TFR_ALL(13) TFR_ALL(15) TFR_ALL(26) TFR_ALL(6) \
    INJ_ALL(KS2, 5u) \
    _Pragma("unroll") \
    for (int s = 0; s < 5; ++s) { \
        uint32_t r0 = h0[2*s] ^ h1[2*s]; \
        uint32_t r1 = h0[2*s+1] ^ h1[2*s+1]; \
        uint32_t w_ = 0u; \
        w_ |= ((float)(r0 >> 9) < xa[s] * 8388608.0f) ? 0x3F80u : 0u; \
        w_ |= ((float)(r1 >> 9) < xb[s] * 8388608.0f) ? 0x3F800000u : 0u; \
        *(uint32_t*)(lds + (abase) + adst[s]) = w_; \
    } }

#define MFMA_CHUNK(s) \
    _Pragma("unroll") \
    for (int m = (s) * 12; m < (s) * 12 + 12; ++m) { \
        const int nt_ = m / 15, r_ = m % 15, pl_ = r_ / 5, mt_ = r_ % 5; \
        acc[mt_][nt_] = __builtin_amdgcn_mfma_f32_16x16x32_bf16( \
            af[mt_], bfr[pl_][nt_], acc[mt_][nt_], 0, 0, 0); \
    }

#define PRELOAD_FRAGS(bufidx) \
    const char* A = lds + (bufidx) * A_BUFSZ; \
    const char* B = lds + LDS_B0 + (bufidx) * B_BUFSZ; \
    bf16x8 af[5]; \
    bf16x8 bfr[3][4]; \
    _Pragma("unroll") \
    for (int mt = 0; mt < 5; ++mt) \
        af[mt] = *(const bf16x8*)(A + a_rd + (mt << 10)); \
    _Pragma("unroll") \
    for (int nt = 0; nt < 4; ++nt) { \
        bfr[0][nt] = *(const bf16x8*)(B + b_rd + (nt << 10)); \
        bfr[1][nt] = *(const bf16x8*)(B + 16384 + b_rd + (nt << 10)); \
        bfr[2][nt] = *(const bf16x8*)(B + 32768 + b_rd + (nt << 10)); \
    }

    // ---- prologue: stage + hash slab 0 into buffers 0 ----
    STAGE_B(0, LDS_B0)
    HASH10(0, 0, false)
    __syncthreads();

    int cur = 0;
#pragma unroll 1
    for (int kw = 0; kw < KWORDS - 1; ++kw) {
        const int  nxt  = cur ^ 1;
        const int  koff = (kw + 1) << 5;              // +32 elems per slab
        const bool tail = (kw == KWORDS - 2);         // hashing slab 24

        // (1) issue next slab's B loads (VMEM queue fills early)
        STAGE_B(koff, LDS_B0 + nxt * B_BUFSZ)

        // (2) hash next slab's A bits: 10 interleaved chains, issue-dense
        HASH10(koff, nxt * A_BUFSZ, tail)

        // (3) preload 17 cur frags, (4) 60 MFMA
        PRELOAD_FRAGS(cur)
        MFMA_CHUNK(0) MFMA_CHUNK(1) MFMA_CHUNK(2) MFMA_CHUNK(3) MFMA_CHUNK(4)

        __syncthreads();   // drains vmcnt (B nxt) + lgkm (A nxt); flip safe
        cur = nxt;
    }

    {   // ---- last slab (kw=24): no hash, no stage ----
        PRELOAD_FRAGS(cur)
        MFMA_CHUNK(0) MFMA_CHUNK(1) MFMA_CHUNK(2) MFMA_CHUNK(3) MFMA_CHUNK(4)
    }
#undef STAGE_B
#undef HASH10
#undef TFR_ALL
#undef INJ_ALL
#undef MFMA_CHUNK
#undef PRELOAD_FRAGS

    // =======================================================================
    // Epilogue: in-block LIF scan + readout (identical to R18).
    // Thread's acc[mt][nt][rr] = I(t = wm*5+mt, j = q*4+rr, col).
    // =======================================================================
    const int c0 = l & 15;
    float b1v[4];
#pragma unroll
    for (int nt = 0; nt < 4; ++nt)
        b1v[nt] = b1[(wn << 6) + (nt << 4) + c0];

    __syncthreads();                       // K-loop LDS dead; reuse
    float* i0   = (float*)lds;             // [80][I0_LDW]: (t0..4 x j) x col
    float* gbuf = (float*)(lds + G_OFF);   // [16][G_LDW]

    if (wm == 0) {                         // park I(t=0..4)
#pragma unroll
        for (int mt = 0; mt < 5; ++mt)
#pragma unroll
            for (int nt = 0; nt < 4; ++nt) {
                int col = (wn << 6) + (nt << 4) + c0;
#pragma unroll
                for (int r = 0; r < 4; ++r) {
                    int j = (q << 2) + r;
                    i0[(mt * 16 + j) * I0_LDW + col] = acc[mt][nt][r] + b1v[nt];
                }
            }
    }
    __syncthreads();

    if (wm == 1) {                         // scan: exact scanout op order
#pragma unroll
        for (int nt = 0; nt < 4; ++nt) {
            int col = (wn << 6) + (nt << 4) + c0;
#pragma unroll
            for (int r = 0; r < 4; ++r) {
                int j = (q << 2) + r;
                float v = 0.f, ga = 0.f, wt = 0.0009765625f;   // 2^-10
#pragma unroll
                for (int t = 0; t < 5; ++t) {
                    float I = i0[(t * 16 + j) * I0_LDW + col];
                    v = v + (I - v) * 0.5f;
                    if (v >= 1.0f) { ga += wt; v = 0.f; }
                    wt += wt;
                }
#pragma unroll
                for (int mt = 0; mt < 5; ++mt) {               // t = 5 + mt
                    float I = acc[mt][nt][r] + b1v[nt];
                    v = v + (I - v) * 0.5f;
                    if (v >= 1.0f) { ga += wt; v = 0.f; }
                    wt += wt;
                }
                gbuf[j * G_LDW + col] = ga;
            }
        }
    }
    __syncthreads();

    {   // readout: wave wv -> rows 2wv, 2wv+1; identical fmaf chain
        const int c = l;
        if (c < NCLS) {
            float brv = br[c] * 0.9990234375f;
#pragma unroll
            for (int rr = 0; rr < 2; ++rr) {
                int j = (wv << 1) + rr;
                const float* gb = &gbuf[j * G_LDW];
                float a = 0.f;
                for (int h4 = 0; h4 < 64; ++h4) {
                    float w0 = Wr[((h4 << 2) + 0) * NCLS + c];
                    float w1 = Wr[((h4 << 2) + 1) * NCLS + c];
                    float w2 = Wr[((h4 << 2) + 2) * NCLS + c];
                    float w3 = Wr[((h4 << 2) + 3) * NCLS + c];
                    float4 gg = *(const float4*)&gb[h4 << 2];
                    a = fmaf(gg.x, w0, a);
                    a = fmaf(gg.y, w1, a);
                    a = fmaf(gg.z, w2, a);
                    a = fmaf(gg.w, w3, a);
                }
                out[(b0 + j) * NCLS + c] = a + brv;
            }
        }
    }
}

extern "C" void kernel_launch(void* const* d_in, const int* in_sizes, int n_in,
                              void* d_out, int out_size, void* d_ws, size_t ws_size,
                              hipStream_t stream) {
    const float* x  = (const float*)d_in[0];
    const float* W1 = (const float*)d_in[1];
    const float* b1 = (const float*)d_in[2];
    const float* Wr = (const float*)d_in[3];
    const float* br = (const float*)d_in[4];
    float* out = (float*)d_out;

    ushort* w1hi  = (ushort*)((char*)d_ws + WS_W1HI_OFF);
    ushort* w1md  = (ushort*)((char*)d_ws + WS_W1MD_OFF);
    ushort* w1lo  = (ushort*)((char*)d_ws + WS_W1LO_OFF);

    splitk_k<<<HID, 256, 0, stream>>>(W1, w1hi, w1md, w1lo);
    fused_gemm_k<<<BATCH / 16, 512, 0, stream>>>(w1hi, w1md, w1lo, b1, x,
                                                 Wr, br, out);
}

// Round 9
// 176.724 us; speedup vs baseline: 1.1091x; 1.1091x over previous
//
#include <hip/hip_runtime.h>
#include <stdint.h>

// ---------------------------------------------------------------------------
// SNN EMNIST forward: T=10, B=4096, IN=784, HID=256, NCLS=47
// R20: fix VALU starvation with WAVES, not per-thread ILP.
// R16/R17/R19 all failed the same way: compiler re-serializes hash chains to
// ~2 live (VGPR 92-100), and at 2 waves/SIMD (1 block/CU, LDS 116KB) the
// port starves at 49-61% VALUBusy. Standalone spikegen at ~5 waves/SIMD ran
// 82%. Change the occupancy, keep the proven scalar hash:
//  - Block: 8 b-rows x 10 t = 80 tile rows x 256 cols, 512 thr = 8 waves of
//    80x32 (acc 40 VGPR). Grid 512 = 2 blocks/CU.
//  - LDS 58KB: A dbuf (2x5KB) + SINGLE-buffered B (48KB). The 2nd barrier
//    per slab is covered by the other block's waves (independent barriers).
//  - __launch_bounds__(512,4) -> <=128 VGPR -> 16 waves/CU = 4/SIMD.
//  - Hash: scalar tf_hash (R18 form), 5 x 1-element tasks/thread (balanced),
//    ds_write_b16 each.
//  - Epilogue: t = 2*mt + (q>>1) -> LIF pairs are lanes l and l^32; exchange
//    via 40x __shfl_xor(.,32); scan + readout op order byte-identical.
// Same threefry/compare/swizzles/MFMA-order -> I bitwise identical ->
// absmax stays 4.882812e-4. splitk unchanged.
// ---------------------------------------------------------------------------

#define T_STEPS 10
#define BATCH   4096
#define IN_DIM  784
#define HID     256
#define NCLS    47
#define KWORDS  25                       // ceil(784/32)
#define KPAD    800                      // 25*32

// d_ws layout (bytes):
//   [46039040, ...)        W1{hi,mid,lo}T : bf16 [256][800], 409600 B each
#define WS_W1HI_OFF 46039040u
#define WS_W1MD_OFF (46039040u + 409600u)
#define WS_W1LO_OFF (46039040u + 819200u)

typedef __attribute__((ext_vector_type(8))) short    bf16x8;
typedef __attribute__((ext_vector_type(4))) float    f32x4;

__device__ __forceinline__ uint32_t rotl32(uint32_t x, uint32_t r) {
    return __builtin_amdgcn_alignbit(x, x, 32u - r);
}

// JAX threefry2x32, key=(0,42), partitionable scheme: out = o0^o1, x0=0, x1=i.
__device__ __forceinline__ uint32_t tf_hash(uint32_t lo) {
    const uint32_t ks1 = 42u;
    const uint32_t ks2 = 0x1BD11BDAu ^ 42u;
    uint32_t x0 = 0u;
    uint32_t x1 = lo + ks1;
#define TF_RND(r) { x0 += x1; x1 = rotl32(x1, r); x1 ^= x0; }
    TF_RND(13) TF_RND(15) TF_RND(26) TF_RND(6)
    x0 += ks1; x1 += ks2 + 1u;
    TF_RND(17) TF_RND(29) TF_RND(16) TF_RND(24)
    x0 += ks2; x1 += 2u;                       // ks0 == 0
    TF_RND(13) TF_RND(15) TF_RND(26) TF_RND(6)
    x1 += ks1 + 3u;                            // x0 += ks0 is a no-op
    TF_RND(17) TF_RND(29) TF_RND(16) TF_RND(24)
    x0 += ks1; x1 += ks2 + 4u;
    TF_RND(13) TF_RND(15) TF_RND(26) TF_RND(6)
    x0 += ks2; x1 += 5u;                       // ks0 == 0
#undef TF_RND
    return x0 ^ x1;
}

// ---------------------------------------------------------------------------
// Kernel B0: split W1 (f32 [784][256]) into transposed bf16 hi/mid/lo
// [256][800]. EXACT: hi+mid+lo == w bitwise.
// ---------------------------------------------------------------------------
__global__ __launch_bounds__(256) void splitk_k(
        const float* __restrict__ W1, ushort* __restrict__ hiT,
        ushort* __restrict__ midT, ushort* __restrict__ loT) {
    int n = blockIdx.x;                  // 0..255
    for (int k = threadIdx.x; k < KPAD; k += 256) {
        float w = (k < IN_DIM) ? W1[k * HID + n] : 0.0f;
        uint32_t u = __float_as_uint(w);
        uint32_t hb = (u + 0x7FFFu + ((u >> 16) & 1u)) >> 16;    // RNE to bf16
        float hf = __uint_as_float(hb << 16);
        float r1 = w - hf;                                       // exact
        uint32_t u1 = __float_as_uint(r1);
        uint32_t mb = (u1 + 0x7FFFu + ((u1 >> 16) & 1u)) >> 16;  // RNE
        float mf2 = __uint_as_float(mb << 16);
        float r2 = r1 - mf2;                                     // exact
        uint32_t u2 = __float_as_uint(r2);
        uint32_t lb = (u2 + 0x7FFFu + ((u2 >> 16) & 1u)) >> 16;  // exact fit
        hiT [n * KPAD + k] = (ushort)hb;
        midT[n * KPAD + k] = (ushort)mb;
        loT [n * KPAD + k] = (ushort)lb;
    }
}

// ---------------------------------------------------------------------------
// Fused spikegen + GEMM + LIF scan + readout.
// Block: 80 tile rows (r = t*8 + j) x 256 cols, 512 thr = 8 waves (1M x 8N),
// wave = 80x32 = 5x2 tiles of 16x16x32. Grid 512 = 2 blocks/CU.
// Per slab: PRELOAD frags (A cur + B) -> hash slab kw+1 (5 x tf_hash ->
// ds_write_b16 into A nxt) -> 30 MFMA -> barrier -> STAGE_B(kw+1) ->
// barrier -> flip. (2 barriers; other block's waves cover the drains.)
// LDS: A bufs [0,10240), B 10240 + {hi 0, mid 16384, lo 32768} = 58KB.
// ---------------------------------------------------------------------------
#define A_BUFSZ 5120                     // 80 rows x 64B
#define LDS_B0  10240
#define G_LDW   260                      // gbuf row pitch (floats)

__global__ __launch_bounds__(512, 4) void fused_gemm_k(
        const ushort* __restrict__ hiT, const ushort* __restrict__ midT,
        const ushort* __restrict__ loT, const float* __restrict__ b1,
        const float* __restrict__ x, const float* __restrict__ Wr,
        const float* __restrict__ br, float* __restrict__ out) {
    __shared__ __align__(16) char lds[59392];    // 58 KB -> 2 blocks/CU

    const int tid = threadIdx.x;
    const int l   = tid & 63;
    const int wv  = tid >> 6;        // 0..7 = N strip (32 cols each)
    const int b0  = blockIdx.x << 3; // 8 batch rows per block

    f32x4 acc[5][2] = {};

    // fragment read addressing (shared swizzle sig for A and B)
    const int q   = l >> 4;
    const int c0  = l & 15;
    const int sig = q ^ (l & 3) ^ ((l >> 2) & 3);
    const int a_rd = (c0 << 6) + (sig << 4);                 // in A buf
    const int b_rd = (wv << 11) + (c0 << 6) + (sig << 4);    // in plane

    // ---- B staging: 1024 slots of 16B per plane, 2 per thread ----
    const ushort* hi_p[2];
    const ushort* md_p[2];
    const ushort* lo_p[2];
    int bdst[2];
#pragma unroll
    for (int i = 0; i < 2; ++i) {
        int s  = (i << 9) + tid;
        int n  = s >> 2;
        int qs = s & 3;
        int qd = qs ^ (n & 3) ^ ((n >> 2) & 3);
        size_t eoff = (size_t)n * KPAD + ((size_t)qd << 3);
        hi_p[i] = hiT  + eoff;
        md_p[i] = midT + eoff;
        lo_p[i] = loT  + eoff;
        bdst[i] = ((i << 9) + (wv << 6)) << 4;    // wave-uniform base
    }

    // ---- A expansion: 2560 single-element tasks/slab = 5 per thread ----
    // tau = tid + 512*s: row = tau>>5 (0..79), element e = tau&31 = tid&31.
    // row r = t*8 + j: t = r>>3, j = r&7; global row g = t*4096 + b0 + j.
    const int eL = tid & 31;
    int      adst[5];
    int      xoff[5];
    uint32_t tib[5];
#pragma unroll
    for (int s = 0; s < 5; ++s) {
        int tau = tid + (s << 9);
        int row = tau >> 5;                        // 0..79
        int p   = eL >> 1;
        int qd  = (p >> 2) ^ (row & 3) ^ ((row >> 2) & 3);
        adst[s] = (row << 6) + (qd << 4) + ((p & 3) << 2) + ((eL & 1) << 1);
        int j   = row & 7;
        int t   = row >> 3;
        int rowg = t * BATCH + b0 + j;
        xoff[s] = (b0 + j) * IN_DIM + eL;
        tib[s]  = (uint32_t)rowg * (uint32_t)IN_DIM + (uint32_t)eL;
    }

#define STAGE_B(koff) \
    _Pragma("unroll") \
    for (int i = 0; i < 2; ++i) { \
        __builtin_amdgcn_global_load_lds( \
            (const __attribute__((address_space(1))) void*)(hi_p[i] + (koff)), \
            (__attribute__((address_space(3))) void*)(lds + LDS_B0 + bdst[i]), \
            16, 0, 0); \
        __builtin_amdgcn_global_load_lds( \
            (const __attribute__((address_space(1))) void*)(md_p[i] + (koff)), \
            (__attribute__((address_space(3))) void*)(lds + LDS_B0 + 16384 + bdst[i]), \
            16, 0, 0); \
        __builtin_amdgcn_global_load_lds( \
            (const __attribute__((address_space(1))) void*)(lo_p[i] + (koff)), \
            (__attribute__((address_space(3))) void*)(lds + LDS_B0 + 32768 + bdst[i]), \
            16, 0, 0); \
    }

// 5 single-element hashes -> ds_write_b16 each. is_tail (slab 24): elements
// e>=16 (k>=784) stay zero (also guards the x OOB read).
#define HASH_SLAB(koff, abase, is_tail) \
    _Pragma("unroll") \
    for (int s = 0; s < 5; ++s) { \
        ushort w_ = 0; \
        if (!(is_tail) || eL < 16) { \
            float    xs = x[xoff[s] + (koff)] * 8388608.0f; \
            uint32_t h  = tf_hash(tib[s] + (uint32_t)(koff)); \
            if ((float)(h >> 9) < xs) w_ = (ushort)0x3F80; \
        } \
        *(ushort*)(lds + (abase) + adst[s]) = w_; \
    }

#define PRELOAD_FRAGS(bufidx) \
    const char* A = lds + (bufidx) * A_BUFSZ; \
    bf16x8 af[5]; \
    bf16x8 bfr[3][2]; \
    _Pragma("unroll") \
    for (int mt = 0; mt < 5; ++mt) \
        af[mt] = *(const bf16x8*)(A + a_rd + (mt << 10)); \
    _Pragma("unroll") \
    for (int nt = 0; nt < 2; ++nt) { \
        bfr[0][nt] = *(const bf16x8*)(lds + LDS_B0 + b_rd + (nt << 10)); \
        bfr[1][nt] = *(const bf16x8*)(lds + LDS_B0 + 16384 + b_rd + (nt << 10)); \
        bfr[2][nt] = *(const bf16x8*)(lds + LDS_B0 + 32768 + b_rd + (nt << 10)); \
    }

#define MFMA_ALL \
    _Pragma("unroll") \
    for (int nt = 0; nt < 2; ++nt) { \
        _Pragma("unroll") \
        for (int mt = 0; mt < 5; ++mt) { \
            acc[mt][nt] = __builtin_amdgcn_mfma_f32_16x16x32_bf16(af[mt], bfr[0][nt], acc[mt][nt], 0, 0, 0); \
            acc[mt][nt] = __builtin_amdgcn_mfma_f32_16x16x32_bf16(af[mt], bfr[1][nt], acc[mt][nt], 0, 0, 0); \
            acc[mt][nt] = __builtin_amdgcn_mfma_f32_16x16x32_bf16(af[mt], bfr[2][nt], acc[mt][nt], 0, 0, 0); \
        } \
    }

    // ---- prologue: stage + hash slab 0 into buffers 0 ----
    STAGE_B(0)
    HASH_SLAB(0, 0, false)
    __syncthreads();

    int cur = 0;
#pragma unroll 1
    for (int kw = 0; kw < KWORDS; ++kw) {
        {
            PRELOAD_FRAGS(cur)
            if (kw < KWORDS - 1) {
                const int koff = (kw + 1) << 5;
                if (kw == KWORDS - 2) { HASH_SLAB(koff, (cur ^ 1) * A_BUFSZ, true) }
                else                  { HASH_SLAB(koff, (cur ^ 1) * A_BUFSZ, false) }
            }
            MFMA_ALL
        }
        __syncthreads();                 // all waves done reading B + A nxt
        if (kw < KWORDS - 1) {
            STAGE_B((kw + 1) << 5)       // overwrite single B buffer
            __syncthreads();             // B[kw+1] ready (vmcnt drained)
        }
        cur ^= 1;
    }
#undef STAGE_B
#undef HASH_SLAB
#undef PRELOAD_FRAGS
#undef MFMA_ALL

    // =======================================================================
    // Epilogue: LIF scan via lane-pair exchange + readout.
    // acc[mt][nt][rr] = I(t = 2*mt + (q>>1), j = (q&1)*4+rr,
    //                     col = wv*32 + nt*16 + c0).  Partner lane = l ^ 32.
    // =======================================================================
    float b1v[2];
#pragma unroll
    for (int nt = 0; nt < 2; ++nt)
        b1v[nt] = b1[(wv << 5) + (nt << 4) + c0];

    float av[5][2][4];
#pragma unroll
    for (int mt = 0; mt < 5; ++mt)
#pragma unroll
        for (int nt = 0; nt < 2; ++nt)
#pragma unroll
            for (int rr = 0; rr < 4; ++rr)
                av[mt][nt][rr] = acc[mt][nt][rr] + b1v[nt];

    const int qh = q >> 1;               // 0: holds even t; 1: holds odd t
    float g[2][4];
#pragma unroll
    for (int nt = 0; nt < 2; ++nt) {
#pragma unroll
        for (int rr = 0; rr < 4; ++rr) {
            float v = 0.f, ga = 0.f, wt = 0.0009765625f;   // 2^-10
#pragma unroll
            for (int m = 0; m < 5; ++m) {
                float pv = __shfl_xor(av[m][nt][rr], 32);  // partner's value
                float Ie = qh ? pv : av[m][nt][rr];        // t = 2m
                float Io = qh ? av[m][nt][rr] : pv;        // t = 2m+1
                v = v + (Ie - v) * 0.5f;
                if (v >= 1.0f) { ga += wt; v = 0.f; }
                wt += wt;
                v = v + (Io - v) * 0.5f;
                if (v >= 1.0f) { ga += wt; v = 0.f; }
                wt += wt;
            }
            g[nt][rr] = ga;
        }
    }

    float* gbuf = (float*)lds;           // [8][G_LDW]; K-loop LDS dead
    // (final K-loop barrier already passed; safe to overwrite)
    if (l < 32) {                        // qh==0 lanes hold canonical g
#pragma unroll
        for (int nt = 0; nt < 2; ++nt)
#pragma unroll
            for (int rr = 0; rr < 4; ++rr) {
                int j   = ((q & 1) << 2) + rr;
                int col = (wv << 5) + (nt << 4) + c0;
                gbuf[j * G_LDW + col] = g[nt][rr];
            }
    }
    __syncthreads();

    {   // readout: wave wv -> batch row b0+wv; identical fmaf chain
        const int c = l;
        if (c < NCLS) {
            const float* gb = &gbuf[wv * G_LDW];
            float a = 0.f;
            for (int h4 = 0; h4 < 64; ++h4) {
                float w0 = Wr[((h4 << 2) + 0) * NCLS + c];
                float w1 = Wr[((h4 << 2) + 1) * NCLS + c];
                float w2 = Wr[((h4 << 2) + 2) * NCLS + c];
                float w3 = Wr[((h4 << 2) + 3) * NCLS + c];
                float4 gg = *(const float4*)&gb[h4 << 2];
                a = fmaf(gg.x, w0, a);
                a = fmaf(gg.y, w1, a);
                a = fmaf(gg.z, w2, a);
                a = fmaf(gg.w, w3, a);
            }
            out[(b0 + wv) * NCLS + c] = a + br[c] * 0.9990234375f;
        }
    }
}

extern "C" void kernel_launch(void* const* d_in, const int* in_sizes, int n_in,
                              void* d_out, int out_size, void* d_ws, size_t ws_size,
                              hipStream_t stream) {
    const float* x  = (const float*)d_in[0];
    const float* W1 = (const float*)d_in[1];
    const float* b1 = (const float*)d_in[2];
    const float* Wr = (const float*)d_in[3];
    const float* br = (const float*)d_in[4];
    float* out = (float*)d_out;

    ushort* w1hi  = (ushort*)((char*)d_ws + WS_W1HI_OFF);
    ushort* w1md  = (ushort*)((char*)d_ws + WS_W1MD_OFF);
    ushort* w1lo  = (ushort*)((char*)d_ws + WS_W1LO_OFF);

    splitk_k<<<HID, 256, 0, stream>>>(W1, w1hi, w1md, w1lo);
    fused_gemm_k<<<BATCH / 8, 512, 0, stream>>>(w1hi, w1md, w1lo, b1, x,
                                                Wr, br, out);
}